// Round 4
// baseline (2532.383 us; speedup 1.0000x reference)
//
#include <hip/hip_runtime.h>

typedef float f32x4 __attribute__((ext_vector_type(4)));
typedef short s16x8 __attribute__((ext_vector_type(8)));
typedef unsigned short u16;

#define B_    256
#define HW_   196
#define E_    1024
#define H_    1024
#define L_    128
#define T_    48
#define FCOUT 1154   // L + H + 2
#define FCPAD 1216   // next multiple of 64
#define G4H   4096   // 4*H

__device__ __forceinline__ u16 f2bf(float x) {
  union { float f; unsigned u; } v; v.f = x;
  unsigned r = v.u + 0x7FFF + ((v.u >> 16) & 1);  // RNE
  return (u16)(r >> 16);
}
__device__ __forceinline__ float sigm(float x) { return 1.f / (1.f + expf(-x)); }

// ---------------------------------------------------------------------------
// Setup: strided fp32 -> bf16 convert (with zero row padding for W_fc)
// ---------------------------------------------------------------------------
__global__ __launch_bounds__(256) void cvt_bf16(
    const float* __restrict__ in, u16* __restrict__ out,
    int src_rows, int in_ld, int in_off, int cols, long total) {
  long idx = (long)blockIdx.x * 256 + threadIdx.x;
  if (idx >= total) return;
  int r = (int)(idx / cols);
  int c = (int)(idx % cols);
  float v = (r < src_rows) ? in[(size_t)r * in_ld + in_off + c] : 0.f;
  out[idx] = f2bf(v);
}

// ---------------------------------------------------------------------------
// img_mean[b][e] = mean over HW of image[b][hw][e]; store bf16
// ---------------------------------------------------------------------------
__global__ __launch_bounds__(256) void img_mean_k(
    const float* __restrict__ image, u16* __restrict__ meanB) {
  int idx = blockIdx.x * 256 + threadIdx.x;   // b*1024 + e
  int b = idx >> 10;
  const float* p = image + (size_t)b * HW_ * E_ + (idx & 1023);
  float s = 0.f;
  #pragma unroll 4
  for (int hw = 0; hw < HW_; ++hw) s += p[(size_t)hw * E_];
  meanB[idx] = f2bf(s * (1.0f / HW_));
}

// ---------------------------------------------------------------------------
// Setup NT GEMM (64x64 tile, 4 waves of 32x32 via 2x2 16x16x32 mfma).
// MODE 0: outF = acc + bias1[n] + bias2[n]     (gates_base)
// MODE 1: outB = bf16(tanh(acc + bias1[n]))    (h0)
// MODE 2: outF = tanh(acc + bias1[n])          (m0)
// ---------------------------------------------------------------------------
template <int MODE>
__global__ __launch_bounds__(256) void gemm_nt(
    const u16* __restrict__ A, int lda, const u16* __restrict__ Bp, int ldb, int K,
    const float* __restrict__ bias1, const float* __restrict__ bias2,
    float* __restrict__ outF, u16* __restrict__ outB, int ldc) {
  __shared__ __align__(16) u16 As[64][72];
  __shared__ __align__(16) u16 Bs[64][72];

  const int m0 = blockIdx.x * 64;
  const int n0 = blockIdx.y * 64;
  const int tid  = threadIdx.x;
  const int lane = tid & 63;
  const int wave = tid >> 6;
  const int wm = wave & 1, wn = wave >> 1;
  const int quad = lane >> 4, l16 = lane & 15;
  const int ar = tid >> 3;
  const int ac = (tid & 7) * 8;

  f32x4 acc[2][2] = {};

  for (int kb = 0; kb < K; kb += 64) {
    __syncthreads();
    #pragma unroll
    for (int p = 0; p < 2; ++p) {
      int r = ar + p * 32;
      *(uint4*)&As[r][ac] = *(const uint4*)&A [(size_t)(m0 + r) * lda + kb + ac];
      *(uint4*)&Bs[r][ac] = *(const uint4*)&Bp[(size_t)(n0 + r) * ldb + kb + ac];
    }
    __syncthreads();
    #pragma unroll
    for (int ks = 0; ks < 64; ks += 32) {
      s16x8 a0v = *(const s16x8*)&As[wm * 32      + l16][ks + quad * 8];
      s16x8 a1v = *(const s16x8*)&As[wm * 32 + 16 + l16][ks + quad * 8];
      s16x8 b0v = *(const s16x8*)&Bs[wn * 32      + l16][ks + quad * 8];
      s16x8 b1v = *(const s16x8*)&Bs[wn * 32 + 16 + l16][ks + quad * 8];
      acc[0][0] = __builtin_amdgcn_mfma_f32_16x16x32_bf16(a0v, b0v, acc[0][0], 0, 0, 0);
      acc[0][1] = __builtin_amdgcn_mfma_f32_16x16x32_bf16(a0v, b1v, acc[0][1], 0, 0, 0);
      acc[1][0] = __builtin_amdgcn_mfma_f32_16x16x32_bf16(a1v, b0v, acc[1][0], 0, 0, 0);
      acc[1][1] = __builtin_amdgcn_mfma_f32_16x16x32_bf16(a1v, b1v, acc[1][1], 0, 0, 0);
    }
  }

  #pragma unroll
  for (int mi = 0; mi < 2; ++mi) {
    #pragma unroll
    for (int ni = 0; ni < 2; ++ni) {
      #pragma unroll
      for (int r = 0; r < 4; ++r) {
        int m = m0 + wm * 32 + mi * 16 + quad * 4 + r;
        int n = n0 + wn * 32 + ni * 16 + l16;
        float v = acc[mi][ni][r];
        if constexpr (MODE == 0) {
          outF[(size_t)m * ldc + n] = v + bias1[n] + bias2[n];
        } else if constexpr (MODE == 1) {
          outB[(size_t)m * ldc + n] = f2bf(tanhf(v + bias1[n]));
        } else {
          outF[(size_t)m * ldc + n] = tanhf(v + bias1[n]);
        }
      }
    }
  }
}

// ---------------------------------------------------------------------------
// glab[t][b][:] = gbase[b][:] + lab(b,t) @ WihL^T   for all t at once.
// M = B*T rows, m = t*256 + b. 64x64 tiles, K = L = 128.
// ---------------------------------------------------------------------------
__global__ __launch_bounds__(256) void glab_k(
    const u16* __restrict__ labB,    // B x T x L
    const u16* __restrict__ WihL,    // 4H x L
    const float* __restrict__ gbase, // B x 4H
    float* __restrict__ glab) {      // T x B x 4H
  __shared__ __align__(16) u16 As[64][72];
  __shared__ __align__(16) u16 Bs[64][72];

  const int m0 = blockIdx.x * 64;
  const int n0 = blockIdx.y * 64;
  const int tid  = threadIdx.x;
  const int lane = tid & 63;
  const int wave = tid >> 6;
  const int wm = wave & 1, wn = wave >> 1;
  const int quad = lane >> 4, l16 = lane & 15;
  const int ar = tid >> 3;
  const int ac = (tid & 7) * 8;
  const int tt = m0 >> 8;            // t is constant within a 64-row tile

  f32x4 acc[2][2] = {};

  #pragma unroll
  for (int kb = 0; kb < L_; kb += 64) {
    __syncthreads();
    #pragma unroll
    for (int p = 0; p < 2; ++p) {
      int r = ar + p * 32;
      int b = (m0 + r) & 255;
      *(uint4*)&As[r][ac] = *(const uint4*)&labB[((size_t)b * T_ + tt) * L_ + kb + ac];
      *(uint4*)&Bs[r][ac] = *(const uint4*)&WihL[(size_t)(n0 + r) * L_ + kb + ac];
    }
    __syncthreads();
    #pragma unroll
    for (int ks = 0; ks < 64; ks += 32) {
      s16x8 a0v = *(const s16x8*)&As[wm * 32      + l16][ks + quad * 8];
      s16x8 a1v = *(const s16x8*)&As[wm * 32 + 16 + l16][ks + quad * 8];
      s16x8 b0v = *(const s16x8*)&Bs[wn * 32      + l16][ks + quad * 8];
      s16x8 b1v = *(const s16x8*)&Bs[wn * 32 + 16 + l16][ks + quad * 8];
      acc[0][0] = __builtin_amdgcn_mfma_f32_16x16x32_bf16(a0v, b0v, acc[0][0], 0, 0, 0);
      acc[0][1] = __builtin_amdgcn_mfma_f32_16x16x32_bf16(a0v, b1v, acc[0][1], 0, 0, 0);
      acc[1][0] = __builtin_amdgcn_mfma_f32_16x16x32_bf16(a1v, b0v, acc[1][0], 0, 0, 0);
      acc[1][1] = __builtin_amdgcn_mfma_f32_16x16x32_bf16(a1v, b1v, acc[1][1], 0, 0, 0);
    }
  }

  #pragma unroll
  for (int mi = 0; mi < 2; ++mi)
    #pragma unroll
    for (int ni = 0; ni < 2; ++ni)
      #pragma unroll
      for (int r = 0; r < 4; ++r) {
        int m = m0 + wm * 32 + mi * 16 + quad * 4 + r;
        int n = n0 + wn * 32 + ni * 16 + l16;
        glab[(size_t)m * G4H + n] = acc[mi][ni][r] + gbase[(size_t)(m & 255) * G4H + n];
      }
}

// ---------------------------------------------------------------------------
// Per-step kernel: gates = glab[t] + h(t-1) @ Whh^T, then LSTM update.
// 256 blocks: mb = bid>>5 (8 b-tiles of 32), jb = bid&31 (32 j-tiles of 32).
// bid%8 == jb%8 -> the 8 blocks sharing a Whh slice land on one XCD; each
// XCD's Whh working set is 1 MB -> stays L2-resident across all 48 steps.
// Each wave = one gate; 32x32 per wave via 2x2 16x16x32 mfma. Double-buffered
// LDS staging (global->reg->LDS) hides load latency behind MFMA.
// ---------------------------------------------------------------------------
__global__ __launch_bounds__(256) void step_k(
    const u16* __restrict__ hprev,   // B x H   (hH + t*B*H)
    u16* __restrict__ hnext,         // B x H   (hH + (t+1)*B*H)
    const u16* __restrict__ WhhB,    // 4H x H
    const float* __restrict__ glab_t,// B x 4H  (glab + t*B*4H)
    float* __restrict__ mS) {        // B x H f32
  __shared__ __align__(16) u16 Ab[2][32][72];
  __shared__ __align__(16) u16 Bb[2][128][72];
  __shared__ float gs[4][32][32];

  const int tid  = threadIdx.x;
  const int lane = tid & 63;
  const int wave = tid >> 6;              // = gate index
  const int quad = lane >> 4, l16 = lane & 15;
  const int jb = blockIdx.x & 31;
  const int mb = blockIdx.x >> 5;
  const int ar = tid >> 3;                // 0..31
  const int ac = (tid & 7) * 8;

  const u16* Ag = hprev + (size_t)(mb * 32) * H_;

  uint4 a_r, b_r[4];
  auto issue = [&](int kb) {
    a_r = *(const uint4*)&Ag[(size_t)ar * H_ + kb + ac];
    #pragma unroll
    for (int q = 0; q < 4; ++q) {
      int rr = ar + q * 32;                       // 0..127
      int grow = (rr >> 5) * H_ + jb * 32 + (rr & 31);
      b_r[q] = *(const uint4*)&WhhB[(size_t)grow * H_ + kb + ac];
    }
  };
  auto commit = [&](int buf) {
    *(uint4*)&Ab[buf][ar][ac] = a_r;
    #pragma unroll
    for (int q = 0; q < 4; ++q) *(uint4*)&Bb[buf][ar + q * 32][ac] = b_r[q];
  };

  f32x4 acc[2][2] = {};
  issue(0);
  commit(0);
  for (int i = 0; i < H_ / 64; ++i) {
    if (i + 1 < H_ / 64) issue((i + 1) * 64);
    __syncthreads();                     // buf[i&1] stores visible
    const int cur = i & 1;
    #pragma unroll
    for (int ks = 0; ks < 64; ks += 32) {
      s16x8 av0 = *(const s16x8*)&Ab[cur][l16][ks + quad * 8];
      s16x8 av1 = *(const s16x8*)&Ab[cur][16 + l16][ks + quad * 8];
      s16x8 bv0 = *(const s16x8*)&Bb[cur][wave * 32      + l16][ks + quad * 8];
      s16x8 bv1 = *(const s16x8*)&Bb[cur][wave * 32 + 16 + l16][ks + quad * 8];
      acc[0][0] = __builtin_amdgcn_mfma_f32_16x16x32_bf16(av0, bv0, acc[0][0], 0, 0, 0);
      acc[0][1] = __builtin_amdgcn_mfma_f32_16x16x32_bf16(av0, bv1, acc[0][1], 0, 0, 0);
      acc[1][0] = __builtin_amdgcn_mfma_f32_16x16x32_bf16(av1, bv0, acc[1][0], 0, 0, 0);
      acc[1][1] = __builtin_amdgcn_mfma_f32_16x16x32_bf16(av1, bv1, acc[1][1], 0, 0, 0);
    }
    __syncthreads();                     // readers done before next commit
    if (i + 1 < H_ / 64) commit((i + 1) & 1);
  }

  // gate exchange: wave g holds gate g's 32x32 tile -> LDS
  #pragma unroll
  for (int mi = 0; mi < 2; ++mi)
    #pragma unroll
    for (int ni = 0; ni < 2; ++ni)
      #pragma unroll
      for (int r = 0; r < 4; ++r)
        gs[wave][mi * 16 + quad * 4 + r][ni * 16 + l16] = acc[mi][ni][r];
  __syncthreads();

  #pragma unroll
  for (int q = 0; q < 4; ++q) {
    int e = tid + q * 256;               // 0..1023 over (bl, jl)
    int bl = e >> 5, jl = e & 31;
    int b = mb * 32 + bl, jg = jb * 32 + jl;
    const float* gb = glab_t + (size_t)b * G4H + jg;
    float gi = gs[0][bl][jl] + gb[0];
    float gf = gs[1][bl][jl] + gb[H_];
    float gg = gs[2][bl][jl] + gb[2 * H_];
    float go = gs[3][bl][jl] + gb[3 * H_];
    size_t sidx = (size_t)b * H_ + jg;
    float m = mS[sidx];
    m = sigm(gf) * m + sigm(gi) * tanhf(gg);
    float h = sigm(go) * tanhf(m);
    mS[sidx] = m;
    hnext[sidx] = f2bf(h);
  }
}

// ---------------------------------------------------------------------------
// Batched fc over all t: M = B*T rows (m = t*256 + b), A row = hH[(t+1)*B+b]
// = (hH + B*H) row m. relu(acc + b_fc) -> masked scatter into the 4 outputs.
// ---------------------------------------------------------------------------
__global__ __launch_bounds__(256) void fc_k(
    const u16* __restrict__ hA,      // (hH + B*H), ld = H, M = B*T
    const u16* __restrict__ WfcB,    // FCPAD x H
    const float* __restrict__ b_fc,
    const int* __restrict__ length,
    float* __restrict__ out) {
  __shared__ __align__(16) u16 As[64][72];
  __shared__ __align__(16) u16 Bs[64][72];

  const int m0 = blockIdx.x * 64;
  const int n0 = blockIdx.y * 64;
  const int tid  = threadIdx.x;
  const int lane = tid & 63;
  const int wave = tid >> 6;
  const int wm = wave & 1, wn = wave >> 1;
  const int quad = lane >> 4, l16 = lane & 15;
  const int ar = tid >> 3;
  const int ac = (tid & 7) * 8;

  f32x4 acc[2][2] = {};

  for (int kb = 0; kb < H_; kb += 64) {
    __syncthreads();
    #pragma unroll
    for (int p = 0; p < 2; ++p) {
      int r = ar + p * 32;
      *(uint4*)&As[r][ac] = *(const uint4*)&hA  [(size_t)(m0 + r) * H_ + kb + ac];
      *(uint4*)&Bs[r][ac] = *(const uint4*)&WfcB[(size_t)(n0 + r) * H_ + kb + ac];
    }
    __syncthreads();
    #pragma unroll
    for (int ks = 0; ks < 64; ks += 32) {
      s16x8 a0v = *(const s16x8*)&As[wm * 32      + l16][ks + quad * 8];
      s16x8 a1v = *(const s16x8*)&As[wm * 32 + 16 + l16][ks + quad * 8];
      s16x8 b0v = *(const s16x8*)&Bs[wn * 32      + l16][ks + quad * 8];
      s16x8 b1v = *(const s16x8*)&Bs[wn * 32 + 16 + l16][ks + quad * 8];
      acc[0][0] = __builtin_amdgcn_mfma_f32_16x16x32_bf16(a0v, b0v, acc[0][0], 0, 0, 0);
      acc[0][1] = __builtin_amdgcn_mfma_f32_16x16x32_bf16(a0v, b1v, acc[0][1], 0, 0, 0);
      acc[1][0] = __builtin_amdgcn_mfma_f32_16x16x32_bf16(a1v, b0v, acc[1][0], 0, 0, 0);
      acc[1][1] = __builtin_amdgcn_mfma_f32_16x16x32_bf16(a1v, b1v, acc[1][1], 0, 0, 0);
    }
  }

  #pragma unroll
  for (int mi = 0; mi < 2; ++mi) {
    #pragma unroll
    for (int ni = 0; ni < 2; ++ni) {
      #pragma unroll
      for (int r = 0; r < 4; ++r) {
        int m = m0 + wm * 32 + mi * 16 + quad * 4 + r;
        int n = n0 + wn * 32 + ni * 16 + l16;
        if (n < FCOUT) {
          int t = m >> 8, b = m & 255;
          float rv = fmaxf(acc[mi][ni][r] + b_fc[n], 0.f);
          float msk = (t < length[b]) ? 1.f : 0.f;
          if (n < L_) {
            out[(size_t)b * (T_ * L_) + t * L_ + n] = rv * msk;
          } else if (n < L_ + H_) {
            out[(size_t)(B_ * T_ * L_) + (size_t)b * (T_ * H_) + t * H_ + (n - L_)] = rv * msk;
          } else if (n == L_ + H_) {
            out[(size_t)B_ * T_ * (L_ + H_) + b * T_ + t] = expf(rv) * msk;
          } else {
            out[(size_t)B_ * T_ * (L_ + H_ + 1) + b * T_ + t] = sigm(rv) * msk;
          }
        }
      }
    }
  }
}

// ---------------------------------------------------------------------------
extern "C" void kernel_launch(void* const* d_in, const int* in_sizes, int n_in,
                              void* d_out, int out_size, void* d_ws, size_t ws_size,
                              hipStream_t stream) {
  const float* image  = (const float*)d_in[0];
  const float* label  = (const float*)d_in[1];
  const int*   length = (const int*)  d_in[2];
  const float* W_h    = (const float*)d_in[3];
  const float* b_h    = (const float*)d_in[4];
  const float* W_m    = (const float*)d_in[5];
  const float* b_m    = (const float*)d_in[6];
  const float* W_ih   = (const float*)d_in[7];
  const float* W_hh   = (const float*)d_in[8];
  const float* b_ih   = (const float*)d_in[9];
  const float* b_hh   = (const float*)d_in[10];
  const float* W_fc   = (const float*)d_in[11];
  const float* b_fc   = (const float*)d_in[12];
  float* out = (float*)d_out;

  char* ws = (char*)d_ws;
  size_t off = 0;
  auto alloc = [&](size_t bytes) -> void* {
    void* p = ws + off;
    off = (off + bytes + 255) & ~(size_t)255;
    return p;
  };
  u16*   meanB = (u16*)  alloc((size_t)B_ * E_ * 2);
  u16*   WhB   = (u16*)  alloc((size_t)H_ * E_ * 2);
  u16*   WmB   = (u16*)  alloc((size_t)H_ * E_ * 2);
  u16*   WihE  = (u16*)  alloc((size_t)G4H * E_ * 2);
  u16*   WihL  = (u16*)  alloc((size_t)G4H * L_ * 2);
  u16*   WhhB  = (u16*)  alloc((size_t)G4H * H_ * 2);
  u16*   WfcB  = (u16*)  alloc((size_t)FCPAD * H_ * 2);
  u16*   labB  = (u16*)  alloc((size_t)B_ * T_ * L_ * 2);
  float* gbase = (float*)alloc((size_t)B_ * G4H * 4);
  float* glab  = (float*)alloc((size_t)T_ * B_ * G4H * 4);   // 201 MB
  u16*   hH    = (u16*)  alloc((size_t)(T_ + 1) * B_ * H_ * 2); // 25.7 MB
  float* mS    = (float*)alloc((size_t)B_ * H_ * 4);

  auto cvt = [&](const float* in, u16* o, int rows, int src_rows, int in_ld,
                 int in_off, int cols) {
    long total = (long)rows * cols;
    int blocks = (int)((total + 255) / 256);
    cvt_bf16<<<blocks, 256, 0, stream>>>(in, o, src_rows, in_ld, in_off, cols, total);
  };

  // --- setup: weight/label conversion to bf16 ---
  cvt(W_h,  WhB,  H_,   H_,   E_,      0,  E_);
  cvt(W_m,  WmB,  H_,   H_,   E_,      0,  E_);
  cvt(W_ih, WihE, G4H,  G4H,  E_ + L_, 0,  E_);   // columns [0, E)
  cvt(W_ih, WihL, G4H,  G4H,  E_ + L_, E_, L_);   // columns [E, E+L)
  cvt(W_hh, WhhB, G4H,  G4H,  H_,      0,  H_);
  cvt(W_fc, WfcB, FCPAD, FCOUT, H_,    0,  H_);   // zero-padded rows
  cvt(label, labB, B_, B_, T_ * L_, 0, T_ * L_);

  img_mean_k<<<(B_ * E_) / 256, 256, 0, stream>>>(image, meanB);

  // --- setup GEMMs ---
  // h0 = tanh(mean @ W_h^T + b_h) -> bf16 into hH slot 0
  gemm_nt<1><<<dim3(B_ / 64, H_ / 64), 256, 0, stream>>>(
      meanB, E_, WhB, E_, E_, b_h, nullptr, nullptr, hH, H_);
  // m0 = tanh(mean @ W_m^T + b_m) -> f32
  gemm_nt<2><<<dim3(B_ / 64, H_ / 64), 256, 0, stream>>>(
      meanB, E_, WmB, E_, E_, b_m, nullptr, mS, nullptr, H_);
  // gates_base = mean @ W_ihE^T + b_ih + b_hh -> f32
  gemm_nt<0><<<dim3(B_ / 64, G4H / 64), 256, 0, stream>>>(
      meanB, E_, WihE, E_, E_, b_ih, b_hh, gbase, nullptr, G4H);
  // glab[t] = gbase + lab_t @ WihL^T, all t
  glab_k<<<dim3(B_ * T_ / 64, G4H / 64), 256, 0, stream>>>(labB, WihL, gbase, glab);

  // --- the scan: gates + update only (fc batched afterwards) ---
  for (int t = 0; t < T_; ++t) {
    step_k<<<256, 256, 0, stream>>>(
        hH + (size_t)t * B_ * H_, hH + (size_t)(t + 1) * B_ * H_,
        WhhB, glab + (size_t)t * B_ * G4H, mS);
  }

  // --- batched fc over all timesteps ---
  fc_k<<<dim3(B_ * T_ / 64, FCPAD / 64), 256, 0, stream>>>(
      hH + (size_t)B_ * H_, WfcB, b_fc, length, out);
}